// Round 1
// baseline (395.060 us; speedup 1.0000x reference)
//
#include <hip/hip_runtime.h>

// Conv2d: input (64,8,256,256) f32, filter (8,8,3,3) OIHW, VALID, stride 1.
// out (64,8,254,254) f32.
//
// Block = 256 threads, one (n, 64x16 output tile, all 8 m).
// LDS: input tile 8c x 18 x 68(pad, 66 used) + filter packed per (m-half, c).
// Thread = 8 consecutive x-pixels x 4 output channels -> 32 accumulators.

#define TW 64
#define TH 16
#define LDS_W 68   // 66 used, padded so rows stay 16B-aligned (68*4=272, %16==0)
#define LDS_H 18   // TH + 2

__global__ __launch_bounds__(256, 3)
void conv2d_tile_kernel(const float* __restrict__ inp,
                        const float* __restrict__ filt,
                        float* __restrict__ out) {
    __shared__ float s_in[8 * LDS_H * LDS_W];   // 39168 B
    __shared__ float s_f[2 * 8 * 36];           // [mg][c][m4*9 + r*3 + s], 2304 B

    const int tid = threadIdx.x;
    const int tx = blockIdx.x;   // 0..3   (x tiles of 64; last covers 62 valid)
    const int ty = blockIdx.y;   // 0..15  (y tiles of 16; last covers 14 valid)
    const int n  = blockIdx.z;   // 0..63
    const int x0 = tx * TW;
    const int y0 = ty * TH;

    const float* in_n = inp + (size_t)n * 8 * 256 * 256;

    // ---- stage input tile: 8 channels x 18 rows x 66 cols (zero-fill OOB) ----
    for (int idx = tid; idx < 8 * LDS_H * 66; idx += 256) {
        int c   = idx / (LDS_H * 66);
        int rem = idx - c * (LDS_H * 66);
        int row = rem / 66;
        int col = rem - row * 66;
        int iy = y0 + row;
        int ix = x0 + col;
        float v = 0.0f;
        if (iy < 256 && ix < 256)
            v = in_n[(c * 256 + iy) * 256 + ix];
        s_in[(c * LDS_H + row) * LDS_W + col] = v;
    }
    // ---- stage filter, packed so each (mg,c) slice is 36 contiguous floats ----
    for (int idx = tid; idx < 576; idx += 256) {
        int m  = idx / 72;          // global layout [m][c][r][s]
        int c  = (idx / 9) % 8;
        int rs = idx % 9;
        s_f[((m >> 2) * 8 + c) * 36 + (m & 3) * 9 + rs] = filt[idx];
    }
    __syncthreads();

    const int xg = tid & 7;          // 8 x-groups of 8 pixels
    const int py = (tid >> 3) & 15;  // row within tile
    const int mg = tid >> 7;         // m-half: 0 -> m 0..3, 1 -> m 4..7
    const int px = xg * 8;

    float acc[4][8];
    #pragma unroll
    for (int m4 = 0; m4 < 4; ++m4)
        #pragma unroll
        for (int i = 0; i < 8; ++i)
            acc[m4][i] = 0.0f;

    for (int c = 0; c < 8; ++c) {
        // filter regs for this (mg, c): 36 floats, contiguous & 16B aligned
        float fr[36];
        const float* fp = &s_f[(mg * 8 + c) * 36];
        #pragma unroll
        for (int j = 0; j < 36; ++j) fr[j] = fp[j];

        const float* ip = &s_in[(c * LDS_H + py) * LDS_W + px];
        #pragma unroll
        for (int r = 0; r < 3; ++r) {
            float iv[10];
            #pragma unroll
            for (int j = 0; j < 10; ++j) iv[j] = ip[r * LDS_W + j];
            #pragma unroll
            for (int s = 0; s < 3; ++s) {
                #pragma unroll
                for (int m4 = 0; m4 < 4; ++m4) {
                    const float fv = fr[m4 * 9 + r * 3 + s];
                    #pragma unroll
                    for (int i = 0; i < 8; ++i)
                        acc[m4][i] = fmaf(iv[i + s], fv, acc[m4][i]);
                }
            }
        }
    }

    // ---- store: 4 channels x 8 pixels, guarded at right/bottom edges ----
    const int oy  = y0 + py;
    const int ox0 = x0 + px;
    if (oy < 254) {
        #pragma unroll
        for (int m4 = 0; m4 < 4; ++m4) {
            float* op = out + ((((size_t)n * 8 + mg * 4 + m4) * 254 + oy) * 254 + ox0);
            if (ox0 + 8 <= 254) {
                #pragma unroll
                for (int i = 0; i < 8; ++i) op[i] = acc[m4][i];
            } else {
                #pragma unroll
                for (int i = 0; i < 8; ++i)
                    if (ox0 + i < 254) op[i] = acc[m4][i];
            }
        }
    }
}

extern "C" void kernel_launch(void* const* d_in, const int* in_sizes, int n_in,
                              void* d_out, int out_size, void* d_ws, size_t ws_size,
                              hipStream_t stream) {
    const float* inp  = (const float*)d_in[0];   // (64,8,256,256)
    const float* filt = (const float*)d_in[1];   // (8,8,3,3)
    float* outp = (float*)d_out;                 // (64,8,254,254)

    dim3 grid(4, 16, 64);
    dim3 block(256);
    conv2d_tile_kernel<<<grid, block, 0, stream>>>(inp, filt, outp);
}